// Round 1
// baseline (1962.337 us; speedup 1.0000x reference)
//
#include <hip/hip_runtime.h>
#include <hip/hip_bf16.h>

typedef __bf16 bf16x8 __attribute__((ext_vector_type(8)));
typedef __bf16 bf16x4 __attribute__((ext_vector_type(4)));
typedef float  f32x4  __attribute__((ext_vector_type(4)));

#define MFMA_BF16(A_, B_, C_) __builtin_amdgcn_mfma_f32_16x16x32_bf16(A_, B_, C_, 0, 0, 0)

static constexpr int    HIDC  = 768;
static constexpr int    BB    = 64;
static constexpr int    LL    = 1024;
static constexpr int    MROWS = BB * LL;          // 65536
static constexpr int    NHEAD = 12;
static constexpr int    HD    = 64;
static constexpr size_t QKV1  = (size_t)BB * NHEAD * LL * HD;   // 50331648 elems

// ---- workspace layout (bytes). total ~512 MB ----
static constexpr size_t OFF_WQKVT = 0;                                    // bf16 [2304][768]
static constexpr size_t OFF_WOT   = OFF_WQKVT + (size_t)2304 * 768 * 2;   // bf16 [768][768]
static constexpr size_t OFF_W1T   = OFF_WOT   + (size_t)768 * 768 * 2;
static constexpr size_t OFF_W2T   = OFF_W1T   + (size_t)768 * 768 * 2;
static constexpr size_t OFF_BQKV  = OFF_W2T   + (size_t)768 * 768 * 2;    // f32 [2304]
static constexpr size_t OFF_C     = OFF_BQKV  + (size_t)2304 * 4;         // f32 [64][4608]
static constexpr size_t OFF_H     = OFF_C     + (size_t)64 * 4608 * 4;    // bf16 [65536][768] (h / h2)
static constexpr size_t OFF_AO    = OFF_H     + (size_t)MROWS * HIDC * 2; // bf16 [65536][768] (attn_out / mlp_h)
static constexpr size_t OFF_QKV   = OFF_AO    + (size_t)MROWS * HIDC * 2; // bf16 [3][B][H][L][D]; later f32 x aliases here

// ---------------- weight transpose + cast: dst[n][k] = bf16(src[k][n]) ----------------
__global__ __launch_bounds__(256) void tcvt_k(const float* __restrict__ src, __bf16* __restrict__ dst) {
    int i = blockIdx.x * 256 + threadIdx.x;     // i = k*768 + n, 768*768 total
    int kk = i / 768, n = i - kk * 768;
    dst[(size_t)n * 768 + kk] = (__bf16)src[i];
}

__global__ __launch_bounds__(256) void bcat_k(const float* __restrict__ bq, const float* __restrict__ bk,
                                              const float* __restrict__ bv, float* __restrict__ bqkv) {
    int i = blockIdx.x * 256 + threadIdx.x;
    if (i < 2304) {
        int w = i / 768, r = i - w * 768;
        const float* p = (w == 0) ? bq : (w == 1) ? bk : bv;
        bqkv[i] = p[r];
    }
}

// ---------------- adaLN: c[64][4608] = silu(cond) @ w_ada + b_ada ----------------
__global__ __launch_bounds__(256) void ada_k(const float* __restrict__ cond, const float* __restrict__ w_ada,
                                             const float* __restrict__ b_ada, float* __restrict__ c) {
    __shared__ float s[8][768];
    const int tid = threadIdx.x;
    const int bt = blockIdx.x / 18;   // 8 b-tiles of 8
    const int nt = blockIdx.x % 18;   // 18 n-tiles of 256
    #pragma unroll
    for (int i = 0; i < 24; ++i) {
        int idx = i * 256 + tid;
        int bb = idx / 768, kk = idx - bb * 768;
        float v = cond[(size_t)(bt * 8 + bb) * 768 + kk];
        s[bb][kk] = v / (1.f + __expf(-v));
    }
    __syncthreads();
    const int n = nt * 256 + tid;
    float acc[8];
    #pragma unroll
    for (int j = 0; j < 8; ++j) acc[j] = 0.f;
    for (int k = 0; k < 768; ++k) {
        float w = w_ada[(size_t)k * 4608 + n];
        #pragma unroll
        for (int j = 0; j < 8; ++j) acc[j] += s[j][k] * w;
    }
    float bias = b_ada[n];
    #pragma unroll
    for (int j = 0; j < 8; ++j) c[(size_t)(bt * 8 + j) * 4608 + n] = acc[j] + bias;
}

// ---------------- fused LayerNorm + modulate -> bf16 ----------------
__global__ __launch_bounds__(256) void ln_mod_k(const float* __restrict__ x,
                                                const float* __restrict__ lns, const float* __restrict__ lnb,
                                                const float* __restrict__ c, int shift_off, int scale_off,
                                                __bf16* __restrict__ out) {
    const int row = blockIdx.x, tid = threadIdx.x;
    const size_t base = (size_t)row * HIDC;
    const int b = row >> 10;
    float v0 = x[base + tid], v1 = x[base + 256 + tid], v2 = x[base + 512 + tid];
    float s = v0 + v1 + v2;
    float ss = v0 * v0 + v1 * v1 + v2 * v2;
    #pragma unroll
    for (int off = 1; off < 64; off <<= 1) { s += __shfl_xor(s, off); ss += __shfl_xor(ss, off); }
    __shared__ float red[8];
    const int wave = tid >> 6, lane = tid & 63;
    if (lane == 0) { red[wave] = s; red[4 + wave] = ss; }
    __syncthreads();
    s  = red[0] + red[1] + red[2] + red[3];
    ss = red[4] + red[5] + red[6] + red[7];
    const float mu   = s * (1.f / 768.f);
    const float var  = ss * (1.f / 768.f) - mu * mu;
    const float rstd = rsqrtf(var + 1e-6f);
    const float* cb = c + (size_t)b * 4608;
    #pragma unroll
    for (int i = 0; i < 3; ++i) {
        int col = i * 256 + tid;
        float v = (i == 0) ? v0 : (i == 1) ? v1 : v2;
        float val = (v - mu) * rstd * lns[col] + lnb[col];
        val = val * (1.f + cb[scale_off + col]) + cb[shift_off + col];
        out[base + col] = (__bf16)val;
    }
}

// ---------------- bf16 MFMA GEMM: C = A[M][768] @ BT^T  (BT is [N][768]) + bias ----------------
// 128x128 tile, BK=32, 4 waves each 64x64. EPI: 0 = QKV scatter, 1 = residual+gate (f32 out), 2 = silu (bf16 out)
template<int EPI>
__global__ __launch_bounds__(256) void gemm_k(const __bf16* __restrict__ A, const __bf16* __restrict__ BT,
                                              const float* __restrict__ bias, int NBLK,
                                              const float* __restrict__ e_res, const float* __restrict__ e_gate,
                                              void* __restrict__ out0) {
    constexpr int K = 768;
    __shared__ __bf16 Als[128][40];
    __shared__ __bf16 Bls[128][40];
    const int tid = threadIdx.x;
    const int mb = blockIdx.x / NBLK, nb = blockIdx.x % NBLK;
    const int wave = tid >> 6, lane = tid & 63;
    const int wm = wave >> 1, wn = wave & 1;
    const int lr = lane & 15, lg = lane >> 4;
    const size_t m0 = (size_t)mb * 128;
    const int n0 = nb * 128;

    f32x4 acc[4][4];
    #pragma unroll
    for (int i = 0; i < 4; ++i)
        #pragma unroll
        for (int j = 0; j < 4; ++j) acc[i][j] = (f32x4){0.f, 0.f, 0.f, 0.f};

    const int g0 = tid, g1 = tid + 256;              // 512 groups of 8 bf16 per tile
    const int ra0 = g0 >> 2, ca0 = (g0 & 3) * 8;
    const int ra1 = g1 >> 2, ca1 = (g1 & 3) * 8;

    const __bf16* Abase = A  + m0 * K;
    const __bf16* Bbase = BT + (size_t)n0 * K;

    bf16x8 sa0 = *(const bf16x8*)(Abase + (size_t)ra0 * K + ca0);
    bf16x8 sa1 = *(const bf16x8*)(Abase + (size_t)ra1 * K + ca1);
    bf16x8 sb0 = *(const bf16x8*)(Bbase + (size_t)ra0 * K + ca0);
    bf16x8 sb1 = *(const bf16x8*)(Bbase + (size_t)ra1 * K + ca1);

    for (int kt = 0; kt < K / 32; ++kt) {
        __syncthreads();
        *(bf16x8*)&Als[ra0][ca0] = sa0;
        *(bf16x8*)&Als[ra1][ca1] = sa1;
        *(bf16x8*)&Bls[ra0][ca0] = sb0;
        *(bf16x8*)&Bls[ra1][ca1] = sb1;
        __syncthreads();
        if (kt + 1 < K / 32) {
            const int k0 = (kt + 1) * 32;
            sa0 = *(const bf16x8*)(Abase + (size_t)ra0 * K + k0 + ca0);
            sa1 = *(const bf16x8*)(Abase + (size_t)ra1 * K + k0 + ca1);
            sb0 = *(const bf16x8*)(Bbase + (size_t)ra0 * K + k0 + ca0);
            sb1 = *(const bf16x8*)(Bbase + (size_t)ra1 * K + k0 + ca1);
        }
        bf16x8 af[4], bf[4];
        #pragma unroll
        for (int mf = 0; mf < 4; ++mf) af[mf] = *(const bf16x8*)&Als[wm * 64 + mf * 16 + lr][lg * 8];
        #pragma unroll
        for (int nf = 0; nf < 4; ++nf) bf[nf] = *(const bf16x8*)&Bls[wn * 64 + nf * 16 + lr][lg * 8];
        #pragma unroll
        for (int mf = 0; mf < 4; ++mf)
            #pragma unroll
            for (int nf = 0; nf < 4; ++nf)
                acc[mf][nf] = MFMA_BF16(af[mf], bf[nf], acc[mf][nf]);
    }

    #pragma unroll
    for (int mf = 0; mf < 4; ++mf) {
        #pragma unroll
        for (int nf = 0; nf < 4; ++nf) {
            #pragma unroll
            for (int r = 0; r < 4; ++r) {
                const int row = wm * 64 + mf * 16 + lg * 4 + r;
                const int col = wn * 64 + nf * 16 + lr;
                const size_t m = m0 + row;
                const int n = n0 + col;
                float val = acc[mf][nf][r] + bias[n];
                if constexpr (EPI == 0) {
                    // scatter to qkv [which][b][h][l][d]
                    int which = n / 768, rem = n - which * 768;
                    int hh = rem >> 6, dd = rem & 63;
                    size_t bI = m >> 10, lI = m & 1023;
                    ((__bf16*)out0)[((((size_t)which * BB + bI) * NHEAD + hh) * LL + lI) * HD + dd] = (__bf16)val;
                } else if constexpr (EPI == 1) {
                    size_t bI = m >> 10;
                    float g = e_gate[bI * 4608 + n];
                    ((float*)out0)[m * HIDC + n] = e_res[m * HIDC + n] + g * val;
                } else {
                    float sv = val / (1.f + __expf(-val));
                    ((__bf16*)out0)[m * HIDC + n] = (__bf16)sv;
                }
            }
        }
    }
}

// ---------------- flash attention: per block one (b,h) x 64 q-rows ----------------
__global__ __launch_bounds__(256) void attn_k(const __bf16* __restrict__ qb, const __bf16* __restrict__ kb,
                                              const __bf16* __restrict__ vb, __bf16* __restrict__ out) {
    __shared__ __bf16 Kls[64][72];
    __shared__ __bf16 Vt[64][72];
    const int tid = threadIdx.x;
    const int bh = blockIdx.x >> 4;
    const int qt = blockIdx.x & 15;
    const int b = bh / NHEAD, h = bh - b * NHEAD;
    const int wave = tid >> 6, lane = tid & 63;
    const int lr = lane & 15, lg = lane >> 4;
    const size_t base = (size_t)bh * LL * HD;

    // wave handles q columns [qt*64 + wave*16, +16); Q fragment in registers
    const __bf16* qrow = qb + base + (size_t)(qt * 64 + wave * 16 + lr) * HD;
    const bf16x8 qf0 = *(const bf16x8*)(qrow + lg * 8);
    const bf16x8 qf1 = *(const bf16x8*)(qrow + 32 + lg * 8);

    f32x4 acc_o[4];
    #pragma unroll
    for (int i = 0; i < 4; ++i) acc_o[i] = (f32x4){0.f, 0.f, 0.f, 0.f};
    float m_run = -1e30f, l_run = 0.f;

    const int gA = tid, gB = tid + 256;
    const int rA = gA >> 3, cA = (gA & 7) * 8;
    const int rB = gB >> 3, cB = (gB & 7) * 8;

    for (int it = 0; it < LL / 64; ++it) {
        const int kv0 = it * 64;
        bf16x8 rk0 = *(const bf16x8*)(kb + base + (size_t)(kv0 + rA) * HD + cA);
        bf16x8 rk1 = *(const bf16x8*)(kb + base + (size_t)(kv0 + rB) * HD + cB);
        bf16x8 rv0 = *(const bf16x8*)(vb + base + (size_t)(kv0 + rA) * HD + cA);
        bf16x8 rv1 = *(const bf16x8*)(vb + base + (size_t)(kv0 + rB) * HD + cB);
        __syncthreads();
        *(bf16x8*)&Kls[rA][cA] = rk0;
        *(bf16x8*)&Kls[rB][cB] = rk1;
        #pragma unroll
        for (int j = 0; j < 8; ++j) { Vt[cA + j][rA] = rv0[j]; Vt[cB + j][rB] = rv1[j]; }
        __syncthreads();

        // S^T[kv][q] = K @ Q^T  (swapped so P is lane-local per q column)
        f32x4 s[4];
        #pragma unroll
        for (int sf = 0; sf < 4; ++sf) {
            s[sf] = (f32x4){0.f, 0.f, 0.f, 0.f};
            const bf16x8 kf0 = *(const bf16x8*)&Kls[sf * 16 + lr][lg * 8];
            const bf16x8 kf1 = *(const bf16x8*)&Kls[sf * 16 + lr][32 + lg * 8];
            s[sf] = MFMA_BF16(kf0, qf0, s[sf]);
            s[sf] = MFMA_BF16(kf1, qf1, s[sf]);
        }
        float tm = -1e30f;
        #pragma unroll
        for (int sf = 0; sf < 4; ++sf)
            #pragma unroll
            for (int r = 0; r < 4; ++r) { float v = s[sf][r] * 0.125f; s[sf][r] = v; tm = fmaxf(tm, v); }
        tm = fmaxf(tm, __shfl_xor(tm, 16));
        tm = fmaxf(tm, __shfl_xor(tm, 32));
        const float mnew = fmaxf(m_run, tm);
        const float corr = __expf(m_run - mnew);
        float rs = 0.f;
        f32x4 p[4];
        #pragma unroll
        for (int sf = 0; sf < 4; ++sf)
            #pragma unroll
            for (int r = 0; r < 4; ++r) { float e = __expf(s[sf][r] - mnew); p[sf][r] = e; rs += e; }
        rs += __shfl_xor(rs, 16);
        rs += __shfl_xor(rs, 32);
        l_run = l_run * corr + rs;
        m_run = mnew;
        #pragma unroll
        for (int of = 0; of < 4; ++of)
            #pragma unroll
            for (int r = 0; r < 4; ++r) acc_o[of][r] *= corr;

        // O^T[d][q] += V^T @ P^T ; k-bijection: j<4 -> kv=ks*32+4g+j, j>=4 -> kv=ks*32+16+4g+(j-4)
        #pragma unroll
        for (int ks = 0; ks < 2; ++ks) {
            bf16x8 pbf;
            #pragma unroll
            for (int j = 0; j < 4; ++j) { pbf[j] = (__bf16)p[2 * ks][j]; pbf[4 + j] = (__bf16)p[2 * ks + 1][j]; }
            #pragma unroll
            for (int of = 0; of < 4; ++of) {
                const bf16x4 v0 = *(const bf16x4*)&Vt[of * 16 + lr][ks * 32 + lg * 4];
                const bf16x4 v1 = *(const bf16x4*)&Vt[of * 16 + lr][ks * 32 + 16 + lg * 4];
                bf16x8 vf;
                #pragma unroll
                for (int j = 0; j < 4; ++j) { vf[j] = v0[j]; vf[4 + j] = v1[j]; }
                acc_o[of] = MFMA_BF16(vf, pbf, acc_o[of]);
            }
        }
    }
    const float inv = 1.f / l_run;
    const int qq = qt * 64 + wave * 16 + lr;
    #pragma unroll
    for (int of = 0; of < 4; ++of)
        #pragma unroll
        for (int r = 0; r < 4; ++r) {
            const int d = of * 16 + lg * 4 + r;
            out[((size_t)b * LL + qq) * HIDC + h * HD + d] = (__bf16)(acc_o[of][r] * inv);
        }
}

extern "C" void kernel_launch(void* const* d_in, const int* in_sizes, int n_in,
                              void* d_out, int out_size, void* d_ws, size_t ws_size,
                              hipStream_t stream) {
    const float* x_img = (const float*)d_in[0];
    const float* cond  = (const float*)d_in[1];
    const float* wq    = (const float*)d_in[2];
    const float* bq    = (const float*)d_in[3];
    const float* wk    = (const float*)d_in[4];
    const float* bk    = (const float*)d_in[5];
    const float* wv    = (const float*)d_in[6];
    const float* bv    = (const float*)d_in[7];
    const float* wo    = (const float*)d_in[8];
    const float* bo    = (const float*)d_in[9];
    const float* w_ada = (const float*)d_in[10];
    const float* b_ada = (const float*)d_in[11];
    const float* w1    = (const float*)d_in[12];
    const float* b1    = (const float*)d_in[13];
    const float* w2    = (const float*)d_in[14];
    const float* b2    = (const float*)d_in[15];
    const float* ln1s  = (const float*)d_in[16];
    const float* ln1b  = (const float*)d_in[17];
    const float* ln2s  = (const float*)d_in[18];
    const float* ln2b  = (const float*)d_in[19];

    char* ws = (char*)d_ws;
    __bf16* wqkvT = (__bf16*)(ws + OFF_WQKVT);
    __bf16* woT   = (__bf16*)(ws + OFF_WOT);
    __bf16* w1T   = (__bf16*)(ws + OFF_W1T);
    __bf16* w2T   = (__bf16*)(ws + OFF_W2T);
    float*  bqkv  = (float*)(ws + OFF_BQKV);
    float*  cbuf  = (float*)(ws + OFF_C);
    __bf16* hbuf  = (__bf16*)(ws + OFF_H);     // h, then h2
    __bf16* aobuf = (__bf16*)(ws + OFF_AO);    // attn_out, then mlp hidden
    __bf16* qkv   = (__bf16*)(ws + OFF_QKV);
    float*  xbuf  = (float*)(ws + OFF_QKV);    // aliases qkv (qkv dead by then)

    dim3 blk(256);

    // weight prep
    tcvt_k<<<2304, blk, 0, stream>>>(wq, wqkvT);
    tcvt_k<<<2304, blk, 0, stream>>>(wk, wqkvT + (size_t)768 * 768);
    tcvt_k<<<2304, blk, 0, stream>>>(wv, wqkvT + (size_t)2 * 768 * 768);
    tcvt_k<<<2304, blk, 0, stream>>>(wo, woT);
    tcvt_k<<<2304, blk, 0, stream>>>(w1, w1T);
    tcvt_k<<<2304, blk, 0, stream>>>(w2, w2T);
    bcat_k<<<9, blk, 0, stream>>>(bq, bk, bv, bqkv);

    // adaLN vector
    ada_k<<<144, blk, 0, stream>>>(cond, w_ada, b_ada, cbuf);

    // h = modulate(LN1(x_img))  [shift_msa@0, scale_msa@768]
    ln_mod_k<<<MROWS, blk, 0, stream>>>(x_img, ln1s, ln1b, cbuf, 0, 768, hbuf);

    // qkv = h @ [wq|wk|wv] + b   (N = 2304)
    gemm_k<0><<<512 * 18, blk, 0, stream>>>(hbuf, wqkvT, bqkv, 18, nullptr, nullptr, (void*)qkv);

    // attention -> attn_out [M][768]
    attn_k<<<BB * NHEAD * 16, blk, 0, stream>>>(qkv, qkv + QKV1, qkv + 2 * QKV1, aobuf);

    // x = x_img + gate_msa * (attn_out @ wo + bo)   (f32, into dead qkv region)
    gemm_k<1><<<512 * 6, blk, 0, stream>>>(aobuf, woT, bo, 6, x_img, cbuf + 2 * 768, (void*)xbuf);

    // h2 = modulate(LN2(x))  [shift_mlp@2304, scale_mlp@3072]
    ln_mod_k<<<MROWS, blk, 0, stream>>>(xbuf, ln2s, ln2b, cbuf, 3 * 768, 4 * 768, hbuf);

    // mlp hidden = silu(h2 @ w1 + b1)
    gemm_k<2><<<512 * 6, blk, 0, stream>>>(hbuf, w1T, b1, 6, nullptr, nullptr, (void*)aobuf);

    // out = x + gate_mlp * (mlp_hidden @ w2 + b2)   (f32 final output)
    gemm_k<1><<<512 * 6, blk, 0, stream>>>(aobuf, w2T, b2, 6, xbuf, cbuf + 5 * 768, d_out);

    (void)in_sizes; (void)n_in; (void)out_size; (void)ws_size;
}

// Round 2
// 1555.830 us; speedup vs baseline: 1.2613x; 1.2613x over previous
//
#include <hip/hip_runtime.h>
#include <hip/hip_bf16.h>

typedef __bf16 bf16x8 __attribute__((ext_vector_type(8)));
typedef __bf16 bf16x4 __attribute__((ext_vector_type(4)));
typedef float  f32x4  __attribute__((ext_vector_type(4)));

#define MFMA_BF16(A_, B_, C_) __builtin_amdgcn_mfma_f32_16x16x32_bf16(A_, B_, C_, 0, 0, 0)

static constexpr int    HIDC  = 768;
static constexpr int    BB    = 64;
static constexpr int    LL    = 1024;
static constexpr int    MROWS = BB * LL;          // 65536
static constexpr int    NHEAD = 12;
static constexpr int    HD    = 64;
static constexpr size_t QKV1  = (size_t)BB * NHEAD * LL * HD;   // 50331648 elems

// ---- workspace layout (bytes) ----
static constexpr size_t OFF_WQKVT = 0;                                    // bf16 [2304][768]
static constexpr size_t OFF_WOT   = OFF_WQKVT + (size_t)2304 * 768 * 2;   // bf16 [768][768]
static constexpr size_t OFF_W1T   = OFF_WOT   + (size_t)768 * 768 * 2;
static constexpr size_t OFF_W2T   = OFF_W1T   + (size_t)768 * 768 * 2;
static constexpr size_t OFF_BQKV  = OFF_W2T   + (size_t)768 * 768 * 2;    // f32 [2304]
static constexpr size_t OFF_C     = OFF_BQKV  + (size_t)2304 * 4;         // f32 [64][4608]
static constexpr size_t OFF_H     = OFF_C     + (size_t)64 * 4608 * 4;    // bf16 h / V^T / h2 (aliased)
static constexpr size_t OFF_AO    = OFF_H     + (size_t)MROWS * HIDC * 2; // bf16 attn_out / mlp_h
static constexpr size_t OFF_QKV   = OFF_AO    + (size_t)MROWS * HIDC * 2; // bf16 [3][B][H][L][D]; later f32 x

__device__ __forceinline__ void async16(const __bf16* g, __bf16* l) {
    __builtin_amdgcn_global_load_lds((const __attribute__((address_space(1))) void*)g,
                                     (__attribute__((address_space(3))) void*)l, 16, 0, 0);
}

// ---------------- weight transpose + cast: dst[n][k] = bf16(src[k][n]) ----------------
__global__ __launch_bounds__(256) void tcvt_k(const float* __restrict__ src, __bf16* __restrict__ dst) {
    int i = blockIdx.x * 256 + threadIdx.x;
    int kk = i / 768, n = i - kk * 768;
    dst[(size_t)n * 768 + kk] = (__bf16)src[i];
}

__global__ __launch_bounds__(256) void bcat_k(const float* __restrict__ bq, const float* __restrict__ bk,
                                              const float* __restrict__ bv, float* __restrict__ bqkv) {
    int i = blockIdx.x * 256 + threadIdx.x;
    if (i < 2304) {
        int w = i / 768, r = i - w * 768;
        const float* p = (w == 0) ? bq : (w == 1) ? bk : bv;
        bqkv[i] = p[r];
    }
}

// ---------------- adaLN: c[64][4608] = silu(cond) @ w_ada + b_ada ----------------
__global__ __launch_bounds__(256) void ada_k(const float* __restrict__ cond, const float* __restrict__ w_ada,
                                             const float* __restrict__ b_ada, float* __restrict__ c) {
    __shared__ float s[8][768];
    const int tid = threadIdx.x;
    const int bt = blockIdx.x / 18;
    const int nt = blockIdx.x % 18;
    #pragma unroll
    for (int i = 0; i < 24; ++i) {
        int idx = i * 256 + tid;
        int bb = idx / 768, kk = idx - bb * 768;
        float v = cond[(size_t)(bt * 8 + bb) * 768 + kk];
        s[bb][kk] = v / (1.f + __expf(-v));
    }
    __syncthreads();
    const int n = nt * 256 + tid;
    float acc[8];
    #pragma unroll
    for (int j = 0; j < 8; ++j) acc[j] = 0.f;
    for (int k = 0; k < 768; ++k) {
        float w = w_ada[(size_t)k * 4608 + n];
        #pragma unroll
        for (int j = 0; j < 8; ++j) acc[j] += s[j][k] * w;
    }
    float bias = b_ada[n];
    #pragma unroll
    for (int j = 0; j < 8; ++j) c[(size_t)(bt * 8 + j) * 4608 + n] = acc[j] + bias;
}

// ---------------- fused LayerNorm + modulate -> bf16 ----------------
__global__ __launch_bounds__(256) void ln_mod_k(const float* __restrict__ x,
                                                const float* __restrict__ lns, const float* __restrict__ lnb,
                                                const float* __restrict__ c, int shift_off, int scale_off,
                                                __bf16* __restrict__ out) {
    const int row = blockIdx.x, tid = threadIdx.x;
    const size_t base = (size_t)row * HIDC;
    const int b = row >> 10;
    float v0 = x[base + tid], v1 = x[base + 256 + tid], v2 = x[base + 512 + tid];
    float s = v0 + v1 + v2;
    float ss = v0 * v0 + v1 * v1 + v2 * v2;
    #pragma unroll
    for (int off = 1; off < 64; off <<= 1) { s += __shfl_xor(s, off); ss += __shfl_xor(ss, off); }
    __shared__ float red[8];
    const int wave = tid >> 6, lane = tid & 63;
    if (lane == 0) { red[wave] = s; red[4 + wave] = ss; }
    __syncthreads();
    s  = red[0] + red[1] + red[2] + red[3];
    ss = red[4] + red[5] + red[6] + red[7];
    const float mu   = s * (1.f / 768.f);
    const float var  = ss * (1.f / 768.f) - mu * mu;
    const float rstd = rsqrtf(var + 1e-6f);
    const float* cb = c + (size_t)b * 4608;
    #pragma unroll
    for (int i = 0; i < 3; ++i) {
        int col = i * 256 + tid;
        float v = (i == 0) ? v0 : (i == 1) ? v1 : v2;
        float val = (v - mu) * rstd * lns[col] + lnb[col];
        val = val * (1.f + cb[scale_off + col]) + cb[shift_off + col];
        out[base + col] = (__bf16)val;
    }
}

// ---------------- V transpose: vt[b][h][d][l] = v[b][h][l][d] ----------------
__global__ __launch_bounds__(256) void vtr_k(const __bf16* __restrict__ v, __bf16* __restrict__ vt) {
    __shared__ __attribute__((aligned(16))) __bf16 t[64][72];
    const int bid = blockIdx.x;            // 768*16
    const int bh = bid >> 4, lt = bid & 15;
    const int l0 = lt * 64;
    const size_t src = (size_t)bh * LL * HD + (size_t)l0 * HD;
    const size_t dst = (size_t)bh * HD * LL + l0;
    const int tid = threadIdx.x;
    const int rA = tid >> 3, cA = (tid & 7) * 8;
    bf16x8 a0 = *(const bf16x8*)(v + src + (size_t)rA * HD + cA);
    bf16x8 a1 = *(const bf16x8*)(v + src + (size_t)(rA + 32) * HD + cA);
    *(bf16x8*)&t[rA][cA] = a0;
    *(bf16x8*)&t[rA + 32][cA] = a1;
    __syncthreads();
    const int r2 = tid & 31, dg = tid >> 5;      // l-pair index, d-group
    bf16x8 b0 = *(const bf16x8*)&t[2 * r2][dg * 8];
    bf16x8 b1 = *(const bf16x8*)&t[2 * r2 + 1][dg * 8];
    #pragma unroll
    for (int j = 0; j < 8; ++j) {
        union { __bf16 h[2]; unsigned u; } pk;
        pk.h[0] = b0[j]; pk.h[1] = b1[j];
        *reinterpret_cast<unsigned*>(vt + dst + (size_t)(dg * 8 + j) * LL + 2 * r2) = pk.u;
    }
}

// ---------------- bf16 MFMA GEMM (m97 structure): C = A[M][768] @ BT^T + bias ----------------
template<int EPI>
__global__ __launch_bounds__(256) void gemm_k(const __bf16* __restrict__ A, const __bf16* __restrict__ BT,
                                              const float* __restrict__ bias, int NBLK,
                                              const float* __restrict__ e_res, const float* __restrict__ e_gate,
                                              void* __restrict__ out0) {
    constexpr int K = 768;
    __shared__ __attribute__((aligned(16))) __bf16 AlsF[128 * 32];
    __shared__ __attribute__((aligned(16))) __bf16 BlsF[128 * 32];
    const int tid = threadIdx.x;
    const int nwg = gridDim.x;
    const int cpx = nwg >> 3;
    const int bid = blockIdx.x;
    const int swz = (bid & 7) * cpx + (bid >> 3);    // XCD-aware (nwg % 8 == 0)
    const int mb = swz / NBLK, nb = swz - mb * NBLK;
    const int wave = tid >> 6, lane = tid & 63;
    const int wm = wave >> 1, wn = wave & 1;
    const int lr = lane & 15, lg = lane >> 4;
    const size_t m0 = (size_t)mb * 128;
    const int n0 = nb * 128;

    f32x4 acc[4][4];
    #pragma unroll
    for (int i = 0; i < 4; ++i)
        #pragma unroll
        for (int j = 0; j < 4; ++j) acc[i][j] = (f32x4){0.f, 0.f, 0.f, 0.f};

    const __bf16* gA0 = A  + (m0 + (tid >> 2)) * K + (tid & 3) * 8;
    const __bf16* gA1 = gA0 + (size_t)64 * K;
    const __bf16* gB0 = BT + ((size_t)n0 + (tid >> 2)) * K + (tid & 3) * 8;
    const __bf16* gB1 = gB0 + (size_t)64 * K;
    __bf16* lA0 = AlsF + tid * 8;
    __bf16* lA1 = AlsF + 2048 + tid * 8;
    __bf16* lB0 = BlsF + tid * 8;
    __bf16* lB1 = BlsF + 2048 + tid * 8;

    for (int kt = 0; kt < K / 32; ++kt) {
        const int k0 = kt * 32;
        __syncthreads();
        async16(gA0 + k0, lA0);
        async16(gA1 + k0, lA1);
        async16(gB0 + k0, lB0);
        async16(gB1 + k0, lB1);
        __syncthreads();
        bf16x8 af[4], bfr[4];
        #pragma unroll
        for (int mf = 0; mf < 4; ++mf) af[mf]  = *(const bf16x8*)&AlsF[(wm * 64 + mf * 16 + lr) * 32 + lg * 8];
        #pragma unroll
        for (int nf = 0; nf < 4; ++nf) bfr[nf] = *(const bf16x8*)&BlsF[(wn * 64 + nf * 16 + lr) * 32 + lg * 8];
        #pragma unroll
        for (int mf = 0; mf < 4; ++mf)
            #pragma unroll
            for (int nf = 0; nf < 4; ++nf)
                acc[mf][nf] = MFMA_BF16(af[mf], bfr[nf], acc[mf][nf]);
    }

    #pragma unroll
    for (int mf = 0; mf < 4; ++mf) {
        #pragma unroll
        for (int nf = 0; nf < 4; ++nf) {
            #pragma unroll
            for (int r = 0; r < 4; ++r) {
                const int row = wm * 64 + mf * 16 + lg * 4 + r;
                const int col = wn * 64 + nf * 16 + lr;
                const size_t m = m0 + row;
                const int n = n0 + col;
                float val = acc[mf][nf][r] + bias[n];
                if constexpr (EPI == 0) {
                    int which = n / 768, rem = n - which * 768;
                    int hh = rem >> 6, dd = rem & 63;
                    size_t bI = m >> 10, lI = m & 1023;
                    ((__bf16*)out0)[((((size_t)which * BB + bI) * NHEAD + hh) * LL + lI) * HD + dd] = (__bf16)val;
                } else if constexpr (EPI == 1) {
                    size_t bI = m >> 10;
                    float g = e_gate[bI * 4608 + n];
                    ((float*)out0)[m * HIDC + n] = e_res[m * HIDC + n] + g * val;
                } else {
                    float sv = val / (1.f + __expf(-val));
                    ((__bf16*)out0)[m * HIDC + n] = (__bf16)sv;
                }
            }
        }
    }
}

// ---------------- flash attention: one (b,h) x 128 q-rows per block ----------------
__global__ __launch_bounds__(256) void attn_k(const __bf16* __restrict__ qb, const __bf16* __restrict__ kb,
                                              const __bf16* __restrict__ vtg, __bf16* __restrict__ out) {
    __shared__ __attribute__((aligned(16))) __bf16 Kls[64][72];
    __shared__ __attribute__((aligned(16))) __bf16 Vls[64][72];
    const int nwg = gridDim.x;       // 6144
    const int cpx = nwg >> 3;
    const int bid = blockIdx.x;
    const int swz = (bid & 7) * cpx + (bid >> 3);
    const int bh = swz >> 3;
    const int qt = swz & 7;
    const int b = bh / NHEAD, h = bh - b * NHEAD;
    const int tid = threadIdx.x;
    const int wave = tid >> 6, lane = tid & 63;
    const int lr = lane & 15, lg = lane >> 4;
    const size_t base  = (size_t)bh * LL * HD;   // q,k layout [bh][l][d]
    const size_t baseT = (size_t)bh * HD * LL;   // vt layout  [bh][d][l]

    const int q0 = qt * 128 + wave * 32;
    bf16x8 qf[2][2];
    #pragma unroll
    for (int qi = 0; qi < 2; ++qi) {
        const __bf16* qrow = qb + base + (size_t)(q0 + qi * 16 + lr) * HD;
        qf[qi][0] = *(const bf16x8*)(qrow + lg * 8);
        qf[qi][1] = *(const bf16x8*)(qrow + 32 + lg * 8);
    }

    f32x4 acc[2][4];
    #pragma unroll
    for (int qi = 0; qi < 2; ++qi)
        #pragma unroll
        for (int i = 0; i < 4; ++i) acc[qi][i] = (f32x4){0.f, 0.f, 0.f, 0.f};
    float m_run[2] = {-1e30f, -1e30f}, l_run[2] = {0.f, 0.f};

    const int rA = tid >> 3, cA = (tid & 7) * 8;     // rA 0..31

    for (int it = 0; it < LL / 64; ++it) {
        const int kv0 = it * 64;
        bf16x8 rk0 = *(const bf16x8*)(kb + base + (size_t)(kv0 + rA) * HD + cA);
        bf16x8 rk1 = *(const bf16x8*)(kb + base + (size_t)(kv0 + rA + 32) * HD + cA);
        bf16x8 rv0 = *(const bf16x8*)(vtg + baseT + (size_t)rA * LL + kv0 + cA);
        bf16x8 rv1 = *(const bf16x8*)(vtg + baseT + (size_t)(rA + 32) * LL + kv0 + cA);
        __syncthreads();
        *(bf16x8*)&Kls[rA][cA] = rk0;
        *(bf16x8*)&Kls[rA + 32][cA] = rk1;
        *(bf16x8*)&Vls[rA][cA] = rv0;
        *(bf16x8*)&Vls[rA + 32][cA] = rv1;
        __syncthreads();

        // S^T[kv][q] = K @ Q^T
        f32x4 s[2][4];
        #pragma unroll
        for (int sf = 0; sf < 4; ++sf) {
            const bf16x8 kf0 = *(const bf16x8*)&Kls[sf * 16 + lr][lg * 8];
            const bf16x8 kf1 = *(const bf16x8*)&Kls[sf * 16 + lr][32 + lg * 8];
            #pragma unroll
            for (int qi = 0; qi < 2; ++qi) {
                f32x4 t = (f32x4){0.f, 0.f, 0.f, 0.f};
                t = MFMA_BF16(kf0, qf[qi][0], t);
                t = MFMA_BF16(kf1, qf[qi][1], t);
                s[qi][sf] = t;
            }
        }
        float corr[2];
        #pragma unroll
        for (int qi = 0; qi < 2; ++qi) {
            float tm = -1e30f;
            #pragma unroll
            for (int sf = 0; sf < 4; ++sf)
                #pragma unroll
                for (int r = 0; r < 4; ++r) { float v = s[qi][sf][r] * 0.125f; s[qi][sf][r] = v; tm = fmaxf(tm, v); }
            tm = fmaxf(tm, __shfl_xor(tm, 16));
            tm = fmaxf(tm, __shfl_xor(tm, 32));
            const float mnew = fmaxf(m_run[qi], tm);
            corr[qi] = __expf(m_run[qi] - mnew);
            float rs = 0.f;
            #pragma unroll
            for (int sf = 0; sf < 4; ++sf)
                #pragma unroll
                for (int r = 0; r < 4; ++r) { float e = __expf(s[qi][sf][r] - mnew); s[qi][sf][r] = e; rs += e; }
            rs += __shfl_xor(rs, 16);
            rs += __shfl_xor(rs, 32);
            l_run[qi] = l_run[qi] * corr[qi] + rs;
            m_run[qi] = mnew;
            #pragma unroll
            for (int of = 0; of < 4; ++of)
                #pragma unroll
                for (int r = 0; r < 4; ++r) acc[qi][of][r] *= corr[qi];
        }
        // O^T[d][q] += V^T @ P^T ; k-bijection: j<4 -> kv=ks*32+4g+j, j>=4 -> +16
        #pragma unroll
        for (int ks = 0; ks < 2; ++ks) {
            bf16x8 pb[2];
            #pragma unroll
            for (int qi = 0; qi < 2; ++qi)
                #pragma unroll
                for (int j = 0; j < 4; ++j) {
                    pb[qi][j]     = (__bf16)s[qi][2 * ks][j];
                    pb[qi][4 + j] = (__bf16)s[qi][2 * ks + 1][j];
                }
            #pragma unroll
            for (int of = 0; of < 4; ++of) {
                const bf16x4 v0 = *(const bf16x4*)&Vls[of * 16 + lr][ks * 32 + lg * 4];
                const bf16x4 v1 = *(const bf16x4*)&Vls[of * 16 + lr][ks * 32 + 16 + lg * 4];
                bf16x8 vf;
                #pragma unroll
                for (int j = 0; j < 4; ++j) { vf[j] = v0[j]; vf[4 + j] = v1[j]; }
                #pragma unroll
                for (int qi = 0; qi < 2; ++qi)
                    acc[qi][of] = MFMA_BF16(vf, pb[qi], acc[qi][of]);
            }
        }
    }
    #pragma unroll
    for (int qi = 0; qi < 2; ++qi) {
        const float inv = 1.f / l_run[qi];
        const int qq = q0 + qi * 16 + lr;
        #pragma unroll
        for (int of = 0; of < 4; ++of)
            #pragma unroll
            for (int r = 0; r < 4; ++r) {
                const int d = of * 16 + lg * 4 + r;
                out[((size_t)b * LL + qq) * HIDC + h * HD + d] = (__bf16)(acc[qi][of][r] * inv);
            }
    }
}

extern "C" void kernel_launch(void* const* d_in, const int* in_sizes, int n_in,
                              void* d_out, int out_size, void* d_ws, size_t ws_size,
                              hipStream_t stream) {
    const float* x_img = (const float*)d_in[0];
    const float* cond  = (const float*)d_in[1];
    const float* wq    = (const float*)d_in[2];
    const float* bq    = (const float*)d_in[3];
    const float* wk    = (const float*)d_in[4];
    const float* bk    = (const float*)d_in[5];
    const float* wv    = (const float*)d_in[6];
    const float* bv    = (const float*)d_in[7];
    const float* wo    = (const float*)d_in[8];
    const float* bo    = (const float*)d_in[9];
    const float* w_ada = (const float*)d_in[10];
    const float* b_ada = (const float*)d_in[11];
    const float* w1    = (const float*)d_in[12];
    const float* b1    = (const float*)d_in[13];
    const float* w2    = (const float*)d_in[14];
    const float* b2    = (const float*)d_in[15];
    const float* ln1s  = (const float*)d_in[16];
    const float* ln1b  = (const float*)d_in[17];
    const float* ln2s  = (const float*)d_in[18];
    const float* ln2b  = (const float*)d_in[19];

    char* ws = (char*)d_ws;
    __bf16* wqkvT = (__bf16*)(ws + OFF_WQKVT);
    __bf16* woT   = (__bf16*)(ws + OFF_WOT);
    __bf16* w1T   = (__bf16*)(ws + OFF_W1T);
    __bf16* w2T   = (__bf16*)(ws + OFF_W2T);
    float*  bqkv  = (float*)(ws + OFF_BQKV);
    float*  cbuf  = (float*)(ws + OFF_C);
    __bf16* hbuf  = (__bf16*)(ws + OFF_H);     // h, then V^T, then h2 (aliased)
    __bf16* vtb   = (__bf16*)(ws + OFF_H);
    __bf16* aobuf = (__bf16*)(ws + OFF_AO);    // attn_out, then mlp hidden
    __bf16* qkv   = (__bf16*)(ws + OFF_QKV);
    float*  xbuf  = (float*)(ws + OFF_QKV);    // aliases qkv (qkv dead by then)

    dim3 blk(256);

    tcvt_k<<<2304, blk, 0, stream>>>(wq, wqkvT);
    tcvt_k<<<2304, blk, 0, stream>>>(wk, wqkvT + (size_t)768 * 768);
    tcvt_k<<<2304, blk, 0, stream>>>(wv, wqkvT + (size_t)2 * 768 * 768);
    tcvt_k<<<2304, blk, 0, stream>>>(wo, woT);
    tcvt_k<<<2304, blk, 0, stream>>>(w1, w1T);
    tcvt_k<<<2304, blk, 0, stream>>>(w2, w2T);
    bcat_k<<<9, blk, 0, stream>>>(bq, bk, bv, bqkv);
    ada_k<<<144, blk, 0, stream>>>(cond, w_ada, b_ada, cbuf);

    // h = modulate(LN1(x_img))
    ln_mod_k<<<MROWS, blk, 0, stream>>>(x_img, ln1s, ln1b, cbuf, 0, 768, hbuf);

    // qkv = h @ [wq|wk|wv] + b
    gemm_k<0><<<512 * 18, blk, 0, stream>>>(hbuf, wqkvT, bqkv, 18, nullptr, nullptr, (void*)qkv);

    // V^T (into dead h buffer)
    vtr_k<<<768 * 16, blk, 0, stream>>>(qkv + 2 * QKV1, vtb);

    // attention -> attn_out
    attn_k<<<BB * NHEAD * 8, blk, 0, stream>>>(qkv, qkv + QKV1, vtb, aobuf);

    // x = x_img + gate_msa * (attn_out @ wo + bo)
    gemm_k<1><<<512 * 6, blk, 0, stream>>>(aobuf, woT, bo, 6, x_img, cbuf + 2 * 768, (void*)xbuf);

    // h2 = modulate(LN2(x))
    ln_mod_k<<<MROWS, blk, 0, stream>>>(xbuf, ln2s, ln2b, cbuf, 3 * 768, 4 * 768, hbuf);

    // mlp hidden = silu(h2 @ w1 + b1)
    gemm_k<2><<<512 * 6, blk, 0, stream>>>(hbuf, w1T, b1, 6, nullptr, nullptr, (void*)aobuf);

    // out = x + gate_mlp * (mlp_hidden @ w2 + b2)
    gemm_k<1><<<512 * 6, blk, 0, stream>>>(aobuf, w2T, b2, 6, xbuf, cbuf + 5 * 768, d_out);

    (void)in_sizes; (void)n_in; (void)out_size; (void)ws_size;
}

// Round 3
// 1348.615 us; speedup vs baseline: 1.4551x; 1.1537x over previous
//
#include <hip/hip_runtime.h>
#include <hip/hip_bf16.h>

typedef __bf16 bf16x8 __attribute__((ext_vector_type(8)));
typedef __bf16 bf16x4 __attribute__((ext_vector_type(4)));
typedef float  f32x4  __attribute__((ext_vector_type(4)));

#define MFMA_BF16(A_, B_, C_) __builtin_amdgcn_mfma_f32_16x16x32_bf16(A_, B_, C_, 0, 0, 0)

static constexpr int    HIDC  = 768;
static constexpr int    BB    = 64;
static constexpr int    LL    = 1024;
static constexpr int    MROWS = BB * LL;          // 65536
static constexpr int    NHEAD = 12;
static constexpr int    HD    = 64;
static constexpr size_t QKV1  = (size_t)BB * NHEAD * LL * HD;   // 50331648 elems

// ---- workspace layout (bytes) ----
static constexpr size_t OFF_WQKVT = 0;                                    // bf16 [2304][768]
static constexpr size_t OFF_WOT   = OFF_WQKVT + (size_t)2304 * 768 * 2;   // bf16 [768][768]
static constexpr size_t OFF_W1T   = OFF_WOT   + (size_t)768 * 768 * 2;
static constexpr size_t OFF_W2T   = OFF_W1T   + (size_t)768 * 768 * 2;
static constexpr size_t OFF_BQKV  = OFF_W2T   + (size_t)768 * 768 * 2;    // f32 [2304]
static constexpr size_t OFF_C     = OFF_BQKV  + (size_t)2304 * 4;         // f32 [64][4608]
static constexpr size_t OFF_H     = OFF_C     + (size_t)64 * 4608 * 4;    // bf16 h / V^T / h2 (aliased)
static constexpr size_t OFF_AO    = OFF_H     + (size_t)MROWS * HIDC * 2; // bf16 attn_out / mlp_h
static constexpr size_t OFF_QKV   = OFF_AO    + (size_t)MROWS * HIDC * 2; // bf16 [3][B][H][L][D]; later f32 x

__device__ __forceinline__ void async16(const __bf16* g, __bf16* l) {
    __builtin_amdgcn_global_load_lds((const __attribute__((address_space(1))) void*)g,
                                     (__attribute__((address_space(3))) void*)l, 16, 0, 0);
}

#define PH_BARRIER() do { __builtin_amdgcn_sched_barrier(0); asm volatile("" ::: "memory"); \
    __builtin_amdgcn_s_barrier(); asm volatile("" ::: "memory"); __builtin_amdgcn_sched_barrier(0); } while (0)

// ---------------- weight transpose + cast: dst[n][k] = bf16(src[k][n]) ----------------
__global__ __launch_bounds__(256) void tcvt_k(const float* __restrict__ src, __bf16* __restrict__ dst) {
    int i = blockIdx.x * 256 + threadIdx.x;
    int kk = i / 768, n = i - kk * 768;
    dst[(size_t)n * 768 + kk] = (__bf16)src[i];
}

__global__ __launch_bounds__(256) void bcat_k(const float* __restrict__ bq, const float* __restrict__ bk,
                                              const float* __restrict__ bv, float* __restrict__ bqkv) {
    int i = blockIdx.x * 256 + threadIdx.x;
    if (i < 2304) {
        int w = i / 768, r = i - w * 768;
        const float* p = (w == 0) ? bq : (w == 1) ? bk : bv;
        bqkv[i] = p[r];
    }
}

// ---------------- adaLN: c[64][4608] = silu(cond) @ w_ada + b_ada ----------------
__global__ __launch_bounds__(256) void ada_k(const float* __restrict__ cond, const float* __restrict__ w_ada,
                                             const float* __restrict__ b_ada, float* __restrict__ c) {
    __shared__ float s[8][768];
    const int tid = threadIdx.x;
    const int bt = blockIdx.x / 18;
    const int nt = blockIdx.x % 18;
    #pragma unroll
    for (int i = 0; i < 24; ++i) {
        int idx = i * 256 + tid;
        int bb = idx / 768, kk = idx - bb * 768;
        float v = cond[(size_t)(bt * 8 + bb) * 768 + kk];
        s[bb][kk] = v / (1.f + __expf(-v));
    }
    __syncthreads();
    const int n = nt * 256 + tid;
    float acc[8];
    #pragma unroll
    for (int j = 0; j < 8; ++j) acc[j] = 0.f;
    for (int k = 0; k < 768; ++k) {
        float w = w_ada[(size_t)k * 4608 + n];
        #pragma unroll
        for (int j = 0; j < 8; ++j) acc[j] += s[j][k] * w;
    }
    float bias = b_ada[n];
    #pragma unroll
    for (int j = 0; j < 8; ++j) c[(size_t)(bt * 8 + j) * 4608 + n] = acc[j] + bias;
}

// ---------------- fused LayerNorm + modulate -> bf16 ----------------
__global__ __launch_bounds__(256) void ln_mod_k(const float* __restrict__ x,
                                                const float* __restrict__ lns, const float* __restrict__ lnb,
                                                const float* __restrict__ c, int shift_off, int scale_off,
                                                __bf16* __restrict__ out) {
    const int row = blockIdx.x, tid = threadIdx.x;
    const size_t base = (size_t)row * HIDC;
    const int b = row >> 10;
    float v0 = x[base + tid], v1 = x[base + 256 + tid], v2 = x[base + 512 + tid];
    float s = v0 + v1 + v2;
    float ss = v0 * v0 + v1 * v1 + v2 * v2;
    #pragma unroll
    for (int off = 1; off < 64; off <<= 1) { s += __shfl_xor(s, off); ss += __shfl_xor(ss, off); }
    __shared__ float red[8];
    const int wave = tid >> 6, lane = tid & 63;
    if (lane == 0) { red[wave] = s; red[4 + wave] = ss; }
    __syncthreads();
    s  = red[0] + red[1] + red[2] + red[3];
    ss = red[4] + red[5] + red[6] + red[7];
    const float mu   = s * (1.f / 768.f);
    const float var  = ss * (1.f / 768.f) - mu * mu;
    const float rstd = rsqrtf(var + 1e-6f);
    const float* cb = c + (size_t)b * 4608;
    #pragma unroll
    for (int i = 0; i < 3; ++i) {
        int col = i * 256 + tid;
        float v = (i == 0) ? v0 : (i == 1) ? v1 : v2;
        float val = (v - mu) * rstd * lns[col] + lnb[col];
        val = val * (1.f + cb[scale_off + col]) + cb[shift_off + col];
        out[base + col] = (__bf16)val;
    }
}

// ---------------- V transpose: vt[b][h][d][l] = v[b][h][l][d] ----------------
__global__ __launch_bounds__(256) void vtr_k(const __bf16* __restrict__ v, __bf16* __restrict__ vt) {
    __shared__ __attribute__((aligned(16))) __bf16 t[64][72];
    const int bid = blockIdx.x;            // 768*16
    const int bh = bid >> 4, lt = bid & 15;
    const int l0 = lt * 64;
    const size_t src = (size_t)bh * LL * HD + (size_t)l0 * HD;
    const size_t dst = (size_t)bh * HD * LL + l0;
    const int tid = threadIdx.x;
    const int rA = tid >> 3, cA = (tid & 7) * 8;
    bf16x8 a0 = *(const bf16x8*)(v + src + (size_t)rA * HD + cA);
    bf16x8 a1 = *(const bf16x8*)(v + src + (size_t)(rA + 32) * HD + cA);
    *(bf16x8*)&t[rA][cA] = a0;
    *(bf16x8*)&t[rA + 32][cA] = a1;
    __syncthreads();
    const int r2 = tid & 31, dg = tid >> 5;
    bf16x8 b0 = *(const bf16x8*)&t[2 * r2][dg * 8];
    bf16x8 b1 = *(const bf16x8*)&t[2 * r2 + 1][dg * 8];
    #pragma unroll
    for (int j = 0; j < 8; ++j) {
        union { __bf16 h[2]; unsigned u; } pk;
        pk.h[0] = b0[j]; pk.h[1] = b1[j];
        *reinterpret_cast<unsigned*>(vt + dst + (size_t)(dg * 8 + j) * LL + 2 * r2) = pk.u;
    }
}

// ================ 256x256 8-phase GEMM (T2+T3+T4+T5), K=768, BK=64 ================
// 8 waves (2M x 4N), per-wave C = 128x64. LDS 128KB = 2 K-tile buffers x (A 32KB + B 32KB).
// Progressive-free staging: during group g's 4 phases stage A(g+1) (p0,p1) and B(g+2) (p2,p3);
// group-boundary wait = counted vmcnt(4) (B(g+2) stays in flight). st_16x32 swizzle both sides.
template<int EPI>
__global__ __launch_bounds__(512, 2) void gemm256_k(const __bf16* __restrict__ A, const __bf16* __restrict__ BT,
                                                    const float* __restrict__ bias, int NBLK,
                                                    const float* __restrict__ e_res, const float* __restrict__ e_gate,
                                                    void* __restrict__ out0) {
    constexpr int K = 768;
    constexpr int NKT = K / 64;           // 12 K-tiles
    __shared__ __attribute__((aligned(16))) unsigned char LDSB[131072];
    const int tid = threadIdx.x;
    const int nwg = gridDim.x;
    const int cpx = nwg >> 3;
    const int bid = blockIdx.x;
    const int swz = (bid & 7) * cpx + (bid >> 3);   // XCD-aware, bijective (nwg%8==0)
    const int mb = swz / NBLK, nb = swz - mb * NBLK;
    const size_t m0 = (size_t)mb * 256;
    const int n0 = nb * 256;
    const int wave = tid >> 6, lane = tid & 63;
    const int wm = wave >> 2, wn = wave & 3;
    const int lr = lane & 15, lg = lane >> 4;

    // stage geometry: thread covers phys bytes [(i*512+tid)*16, +16) of a 16KB half-tile region
    int prow[2], pcol[2], pphys[2];
    #pragma unroll
    for (int i = 0; i < 2; ++i) {
        int p = (i * 512 + tid) * 16;
        int Lb = p ^ (((p >> 9) & 1) << 5);          // st_16x32 involution
        prow[i] = Lb >> 7;
        pcol[i] = (Lb & 127) >> 1;
        pphys[i] = p;
    }
    auto STAGE = [&](const __bf16* gbase, size_t rowstart, int kt, int regoff) {
        #pragma unroll
        for (int i = 0; i < 2; ++i) {
            const __bf16* g = gbase + (rowstart + (size_t)prow[i]) * K + kt * 64 + pcol[i];
            async16(g, (__bf16*)(LDSB + regoff + pphys[i]));
        }
    };
    auto AFRAG = [&](int db, int mf, int ks) -> bf16x8 {
        int Lb = (mf * 16 + lr) * 128 + ks * 64 + lg * 16;
        int ph = Lb ^ (((Lb >> 9) & 1) << 5);
        return *(const bf16x8*)(LDSB + db * 65536 + wm * 16384 + ph);
    };
    auto BFRAG = [&](int db, int nf, int ks) -> bf16x8 {
        int Lb = ((wn & 1) * 64 + nf * 16 + lr) * 128 + ks * 64 + lg * 16;
        int ph = Lb ^ (((Lb >> 9) & 1) << 5);
        return *(const bf16x8*)(LDSB + db * 65536 + 32768 + (wn >> 1) * 16384 + ph);
    };

    f32x4 acc[8][4];
    #pragma unroll
    for (int i = 0; i < 8; ++i)
        #pragma unroll
        for (int j = 0; j < 4; ++j) acc[i][j] = (f32x4){0.f, 0.f, 0.f, 0.f};
    bf16x8 Af[4][2], Bf[4][2];

    // ---- prologue: B(0), A(0), B(1); keep B(1) in flight ----
    STAGE(BT, (size_t)n0,       0, 32768);
    STAGE(BT, (size_t)n0 + 128, 0, 49152);
    STAGE(A,  m0,               0, 0);
    STAGE(A,  m0 + 128,         0, 16384);
    STAGE(BT, (size_t)n0,       1, 65536 + 32768);
    STAGE(BT, (size_t)n0 + 128, 1, 65536 + 49152);
    asm volatile("s_waitcnt vmcnt(4)" ::: "memory");
    PH_BARRIER();

    #pragma unroll 2
    for (int g = 0; g < NKT; ++g) {
        const int db = g & 1, dbn = db ^ 1;
        // ---- phase 0: q(mf0-3, nf0-1) ----
        if (g + 1 < NKT) STAGE(A, m0, g + 1, dbn * 65536);
        #pragma unroll
        for (int mf = 0; mf < 4; ++mf) { Af[mf][0] = AFRAG(db, mf, 0); Af[mf][1] = AFRAG(db, mf, 1); }
        #pragma unroll
        for (int nf = 0; nf < 2; ++nf) { Bf[nf][0] = BFRAG(db, nf, 0); Bf[nf][1] = BFRAG(db, nf, 1); }
        __builtin_amdgcn_s_setprio(1);
        #pragma unroll
        for (int ks = 0; ks < 2; ++ks)
            #pragma unroll
            for (int mf = 0; mf < 4; ++mf)
                #pragma unroll
                for (int nf = 0; nf < 2; ++nf)
                    acc[mf][nf] = MFMA_BF16(Af[mf][ks], Bf[nf][ks], acc[mf][nf]);
        __builtin_amdgcn_s_setprio(0);
        PH_BARRIER();
        // ---- phase 1: q(mf0-3, nf2-3) ----
        if (g + 1 < NKT) STAGE(A, m0 + 128, g + 1, dbn * 65536 + 16384);
        #pragma unroll
        for (int nf = 2; nf < 4; ++nf) { Bf[nf][0] = BFRAG(db, nf, 0); Bf[nf][1] = BFRAG(db, nf, 1); }
        __builtin_amdgcn_s_setprio(1);
        #pragma unroll
        for (int ks = 0; ks < 2; ++ks)
            #pragma unroll
            for (int mf = 0; mf < 4; ++mf)
                #pragma unroll
                for (int nf = 2; nf < 4; ++nf)
                    acc[mf][nf] = MFMA_BF16(Af[mf][ks], Bf[nf][ks], acc[mf][nf]);
        __builtin_amdgcn_s_setprio(0);
        PH_BARRIER();
        // ---- phase 2: q(mf4-7, nf0-1) ----
        if (g + 2 < NKT) STAGE(BT, (size_t)n0, g + 2, db * 65536 + 32768);
        #pragma unroll
        for (int mf = 0; mf < 4; ++mf) { Af[mf][0] = AFRAG(db, mf + 4, 0); Af[mf][1] = AFRAG(db, mf + 4, 1); }
        __builtin_amdgcn_s_setprio(1);
        #pragma unroll
        for (int ks = 0; ks < 2; ++ks)
            #pragma unroll
            for (int mf = 0; mf < 4; ++mf)
                #pragma unroll
                for (int nf = 0; nf < 2; ++nf)
                    acc[mf + 4][nf] = MFMA_BF16(Af[mf][ks], Bf[nf][ks], acc[mf + 4][nf]);
        __builtin_amdgcn_s_setprio(0);
        PH_BARRIER();
        // ---- phase 3: q(mf4-7, nf2-3) ----
        if (g + 2 < NKT) STAGE(BT, (size_t)n0 + 128, g + 2, db * 65536 + 49152);
        __builtin_amdgcn_s_setprio(1);
        #pragma unroll
        for (int ks = 0; ks < 2; ++ks)
            #pragma unroll
            for (int mf = 0; mf < 4; ++mf)
                #pragma unroll
                for (int nf = 2; nf < 4; ++nf)
                    acc[mf + 4][nf] = MFMA_BF16(Af[mf][ks], Bf[nf][ks], acc[mf + 4][nf]);
        __builtin_amdgcn_s_setprio(0);
        // ---- group boundary: counted vmcnt, never 0 until the tail ----
        if (g < NKT - 2)       asm volatile("s_waitcnt vmcnt(4)" ::: "memory");
        else if (g == NKT - 2) asm volatile("s_waitcnt vmcnt(0)" ::: "memory");
        if (g + 1 < NKT) PH_BARRIER();
    }

    // ---- epilogue ----
    #pragma unroll
    for (int mf = 0; mf < 8; ++mf) {
        #pragma unroll
        for (int nf = 0; nf < 4; ++nf) {
            #pragma unroll
            for (int r = 0; r < 4; ++r) {
                const int row = wm * 128 + mf * 16 + lg * 4 + r;
                const int col = wn * 64 + nf * 16 + lr;
                const size_t m = m0 + row;
                const int n = n0 + col;
                float val = acc[mf][nf][r] + bias[n];
                if constexpr (EPI == 0) {
                    int which = n / 768, rem = n - which * 768;
                    int hh = rem >> 6, dd = rem & 63;
                    size_t bI = m >> 10, lI = m & 1023;
                    ((__bf16*)out0)[((((size_t)which * BB + bI) * NHEAD + hh) * LL + lI) * HD + dd] = (__bf16)val;
                } else if constexpr (EPI == 1) {
                    size_t bI = m >> 10;
                    float gg = e_gate[bI * 4608 + n];
                    ((float*)out0)[m * HIDC + n] = e_res[m * HIDC + n] + gg * val;
                } else {
                    float sv = val / (1.f + __expf(-val));
                    ((__bf16*)out0)[m * HIDC + n] = (__bf16)sv;
                }
            }
        }
    }
}

// ---------------- flash attention: one (b,h) x 128 q-rows per block ----------------
__global__ __launch_bounds__(256) void attn_k(const __bf16* __restrict__ qb, const __bf16* __restrict__ kb,
                                              const __bf16* __restrict__ vtg, __bf16* __restrict__ out) {
    __shared__ __attribute__((aligned(16))) __bf16 Kls[64][72];
    __shared__ __attribute__((aligned(16))) __bf16 Vls[64][72];
    const int nwg = gridDim.x;       // 6144
    const int cpx = nwg >> 3;
    const int bid = blockIdx.x;
    const int swz = (bid & 7) * cpx + (bid >> 3);
    const int bh = swz >> 3;
    const int qt = swz & 7;
    const int b = bh / NHEAD, h = bh - b * NHEAD;
    const int tid = threadIdx.x;
    const int wave = tid >> 6, lane = tid & 63;
    const int lr = lane & 15, lg = lane >> 4;
    const size_t base  = (size_t)bh * LL * HD;   // q,k layout [bh][l][d]
    const size_t baseT = (size_t)bh * HD * LL;   // vt layout  [bh][d][l]

    const int q0 = qt * 128 + wave * 32;
    bf16x8 qf[2][2];
    #pragma unroll
    for (int qi = 0; qi < 2; ++qi) {
        const __bf16* qrow = qb + base + (size_t)(q0 + qi * 16 + lr) * HD;
        qf[qi][0] = *(const bf16x8*)(qrow + lg * 8);
        qf[qi][1] = *(const bf16x8*)(qrow + 32 + lg * 8);
    }

    f32x4 acc[2][4];
    #pragma unroll
    for (int qi = 0; qi < 2; ++qi)
        #pragma unroll
        for (int i = 0; i < 4; ++i) acc[qi][i] = (f32x4){0.f, 0.f, 0.f, 0.f};
    float m_run[2] = {-1e30f, -1e30f}, l_run[2] = {0.f, 0.f};

    const int rA = tid >> 3, cA = (tid & 7) * 8;     // rA 0..31

    for (int it = 0; it < LL / 64; ++it) {
        const int kv0 = it * 64;
        bf16x8 rk0 = *(const bf16x8*)(kb + base + (size_t)(kv0 + rA) * HD + cA);
        bf16x8 rk1 = *(const bf16x8*)(kb + base + (size_t)(kv0 + rA + 32) * HD + cA);
        bf16x8 rv0 = *(const bf16x8*)(vtg + baseT + (size_t)rA * LL + kv0 + cA);
        bf16x8 rv1 = *(const bf16x8*)(vtg + baseT + (size_t)(rA + 32) * LL + kv0 + cA);
        __syncthreads();
        *(bf16x8*)&Kls[rA][cA] = rk0;
        *(bf16x8*)&Kls[rA + 32][cA] = rk1;
        *(bf16x8*)&Vls[rA][cA] = rv0;
        *(bf16x8*)&Vls[rA + 32][cA] = rv1;
        __syncthreads();

        f32x4 s[2][4];
        #pragma unroll
        for (int sf = 0; sf < 4; ++sf) {
            const bf16x8 kf0 = *(const bf16x8*)&Kls[sf * 16 + lr][lg * 8];
            const bf16x8 kf1 = *(const bf16x8*)&Kls[sf * 16 + lr][32 + lg * 8];
            #pragma unroll
            for (int qi = 0; qi < 2; ++qi) {
                f32x4 t = (f32x4){0.f, 0.f, 0.f, 0.f};
                t = MFMA_BF16(kf0, qf[qi][0], t);
                t = MFMA_BF16(kf1, qf[qi][1], t);
                s[qi][sf] = t;
            }
        }
        float corr[2];
        #pragma unroll
        for (int qi = 0; qi < 2; ++qi) {
            float tm = -1e30f;
            #pragma unroll
            for (int sf = 0; sf < 4; ++sf)
                #pragma unroll
                for (int r = 0; r < 4; ++r) { float v = s[qi][sf][r] * 0.125f; s[qi][sf][r] = v; tm = fmaxf(tm, v); }
            tm = fmaxf(tm, __shfl_xor(tm, 16));
            tm = fmaxf(tm, __shfl_xor(tm, 32));
            const float mnew = fmaxf(m_run[qi], tm);
            corr[qi] = __expf(m_run[qi] - mnew);
            float rs = 0.f;
            #pragma unroll
            for (int sf = 0; sf < 4; ++sf)
                #pragma unroll
                for (int r = 0; r < 4; ++r) { float e = __expf(s[qi][sf][r] - mnew); s[qi][sf][r] = e; rs += e; }
            rs += __shfl_xor(rs, 16);
            rs += __shfl_xor(rs, 32);
            l_run[qi] = l_run[qi] * corr[qi] + rs;
            m_run[qi] = mnew;
            #pragma unroll
            for (int of = 0; of < 4; ++of)
                #pragma unroll
                for (int r = 0; r < 4; ++r) acc[qi][of][r] *= corr[qi];
        }
        #pragma unroll
        for (int ks = 0; ks < 2; ++ks) {
            bf16x8 pb[2];
            #pragma unroll
            for (int qi = 0; qi < 2; ++qi)
                #pragma unroll
                for (int j = 0; j < 4; ++j) {
                    pb[qi][j]     = (__bf16)s[qi][2 * ks][j];
                    pb[qi][4 + j] = (__bf16)s[qi][2 * ks + 1][j];
                }
            #pragma unroll
            for (int of = 0; of < 4; ++of) {
                const bf16x4 v0 = *(const bf16x4*)&Vls[of * 16 + lr][ks * 32 + lg * 4];
                const bf16x4 v1 = *(const bf16x4*)&Vls[of * 16 + lr][ks * 32 + 16 + lg * 4];
                bf16x8 vf;
                #pragma unroll
                for (int j = 0; j < 4; ++j) { vf[j] = v0[j]; vf[4 + j] = v1[j]; }
                #pragma unroll
                for (int qi = 0; qi < 2; ++qi)
                    acc[qi][of] = MFMA_BF16(vf, pb[qi], acc[qi][of]);
            }
        }
    }
    #pragma unroll
    for (int qi = 0; qi < 2; ++qi) {
        const float inv = 1.f / l_run[qi];
        const int qq = q0 + qi * 16 + lr;
        #pragma unroll
        for (int of = 0; of < 4; ++of)
            #pragma unroll
            for (int r = 0; r < 4; ++r) {
                const int d = of * 16 + lg * 4 + r;
                out[((size_t)b * LL + qq) * HIDC + h * HD + d] = (__bf16)(acc[qi][of][r] * inv);
            }
    }
}

extern "C" void kernel_launch(void* const* d_in, const int* in_sizes, int n_in,
                              void* d_out, int out_size, void* d_ws, size_t ws_size,
                              hipStream_t stream) {
    const float* x_img = (const float*)d_in[0];
    const float* cond  = (const float*)d_in[1];
    const float* wq    = (const float*)d_in[2];
    const float* bq    = (const float*)d_in[3];
    const float* wk    = (const float*)d_in[4];
    const float* bk    = (const float*)d_in[5];
    const float* wv    = (const float*)d_in[6];
    const float* bv    = (const float*)d_in[7];
    const float* wo    = (const float*)d_in[8];
    const float* bo    = (const float*)d_in[9];
    const float* w_ada = (const float*)d_in[10];
    const float* b_ada = (const float*)d_in[11];
    const float* w1    = (const float*)d_in[12];
    const float* b1    = (const float*)d_in[13];
    const float* w2    = (const float*)d_in[14];
    const float* b2    = (const float*)d_in[15];
    const float* ln1s  = (const float*)d_in[16];
    const float* ln1b  = (const float*)d_in[17];
    const float* ln2s  = (const float*)d_in[18];
    const float* ln2b  = (const float*)d_in[19];

    char* ws = (char*)d_ws;
    __bf16* wqkvT = (__bf16*)(ws + OFF_WQKVT);
    __bf16* woT   = (__bf16*)(ws + OFF_WOT);
    __bf16* w1T   = (__bf16*)(ws + OFF_W1T);
    __bf16* w2T   = (__bf16*)(ws + OFF_W2T);
    float*  bqkv  = (float*)(ws + OFF_BQKV);
    float*  cbuf  = (float*)(ws + OFF_C);
    __bf16* hbuf  = (__bf16*)(ws + OFF_H);
    __bf16* vtb   = (__bf16*)(ws + OFF_H);
    __bf16* aobuf = (__bf16*)(ws + OFF_AO);
    __bf16* qkv   = (__bf16*)(ws + OFF_QKV);
    float*  xbuf  = (float*)(ws + OFF_QKV);

    dim3 blk(256);
    dim3 blk512(512);

    tcvt_k<<<2304, blk, 0, stream>>>(wq, wqkvT);
    tcvt_k<<<2304, blk, 0, stream>>>(wk, wqkvT + (size_t)768 * 768);
    tcvt_k<<<2304, blk, 0, stream>>>(wv, wqkvT + (size_t)2 * 768 * 768);
    tcvt_k<<<2304, blk, 0, stream>>>(wo, woT);
    tcvt_k<<<2304, blk, 0, stream>>>(w1, w1T);
    tcvt_k<<<2304, blk, 0, stream>>>(w2, w2T);
    bcat_k<<<9, blk, 0, stream>>>(bq, bk, bv, bqkv);
    ada_k<<<144, blk, 0, stream>>>(cond, w_ada, b_ada, cbuf);

    // h = modulate(LN1(x_img))
    ln_mod_k<<<MROWS, blk, 0, stream>>>(x_img, ln1s, ln1b, cbuf, 0, 768, hbuf);

    // qkv = h @ [wq|wk|wv] + b   (M=65536, N=2304)
    gemm256_k<0><<<2304, blk512, 0, stream>>>(hbuf, wqkvT, bqkv, 9, nullptr, nullptr, (void*)qkv);

    // V^T (into dead h buffer)
    vtr_k<<<768 * 16, blk, 0, stream>>>(qkv + 2 * QKV1, vtb);

    // attention -> attn_out
    attn_k<<<BB * NHEAD * 8, blk, 0, stream>>>(qkv, qkv + QKV1, vtb, aobuf);

    // x = x_img + gate_msa * (attn_out @ wo + bo)
    gemm256_k<1><<<768, blk512, 0, stream>>>(aobuf, woT, bo, 3, x_img, cbuf + 2 * 768, (void*)xbuf);

    // h2 = modulate(LN2(x))
    ln_mod_k<<<MROWS, blk, 0, stream>>>(xbuf, ln2s, ln2b, cbuf, 3 * 768, 4 * 768, hbuf);

    // mlp hidden = silu(h2 @ w1 + b1)
    gemm256_k<2><<<768, blk512, 0, stream>>>(hbuf, w1T, b1, 3, nullptr, nullptr, (void*)aobuf);

    // out = x + gate_mlp * (mlp_hidden @ w2 + b2)
    gemm256_k<1><<<768, blk512, 0, stream>>>(aobuf, w2T, b2, 3, xbuf, cbuf + 5 * 768, d_out);

    (void)in_sizes; (void)n_in; (void)out_size; (void)ws_size;
}